// Round 4
// baseline (1110.487 us; speedup 1.0000x reference)
//
#include <hip/hip_runtime.h>
#include <hip/hip_cooperative_groups.h>
#include <cstdint>
#include <cstddef>

namespace cg = cooperative_groups;

// Problem constants (fixed by reference setup_inputs)
#define HW_      65536     // 256*256
#define NB       8         // batch
#define NC       8         // colour dim
#define NF       64        // feature dim
#define NK       8         // K_STEPS
#define NT       256       // threads per block
#define PX       2         // pixels per thread
#define CHUNK_PX (NT * PX)       // 512 pixels per block
#define NCHUNK   (HW_ / CHUNK_PX) // 128 blocks per batch -> 1024 blocks total

// d_out layout (floats):
//   log_m_k : (NK+1)*NB*HW_
//   log_s_k : (NK+1)*NB*HW_
//   colour  : NB*NC*HW_
//   seeds   : NK*NB*NC
#define LMK_SZ ((size_t)(NK + 1) * NB * HW_)
#define COL_SZ ((size_t)NB * NC * HW_)

__device__ __forceinline__ void argmax_cmp(float& bv, int& bi, float ov, int oi) {
    if (ov > bv || (ov == bv && oi < bi)) { bv = ov; bi = oi; }
}

__device__ __forceinline__ void wave_argmax(float& bv, int& bi) {
#pragma unroll
    for (int off = 32; off > 0; off >>= 1) {
        float ov = __shfl_down(bv, off);
        int   oi = __shfl_down(bi, off);
        argmax_cmp(bv, bi, ov, oi);
    }
}

// One persistent cooperative kernel: colour head + 8 scan steps.
// Per thread: 2 pixels. colour (16f), rand (2f), running log_s (2f) live in
// registers across all steps. Cross-block argmax via partials in d_ws +
// grid.sync() (double-buffered by step parity).
__global__ __launch_bounds__(NT, 4)
void fused_sbp_kernel(const float* __restrict__ feat, const float* __restrict__ Wm,
                      const float* __restrict__ bias, const float* __restrict__ log_sigma_p,
                      const float* __restrict__ rand_pix,
                      float* __restrict__ log_m_k, float* __restrict__ log_s_k,
                      float* __restrict__ colour, float* __restrict__ seeds,
                      float* __restrict__ pv, int* __restrict__ pi) {
    cg::grid_group grid = cg::this_grid();

    const int tid   = threadIdx.x;
    const int chunk = blockIdx.x;   // 0..NCHUNK-1
    const int b     = blockIdx.y;   // 0..NB-1
    const int lane  = tid & 63;
    const int wid   = tid >> 6;

    __shared__ float sW[NC * NF];
    __shared__ float sB[NC];
    __shared__ float sSeed[NC];
    __shared__ float swv[NT / 64];
    __shared__ int   swi[NT / 64];
    __shared__ float sRes;
    __shared__ int   sResI;

    for (int i = tid; i < NC * NF; i += NT) sW[i] = Wm[i];
    if (tid < NC) sB[tid] = bias[tid];
    __syncthreads();

    const int    hw0  = chunk * CHUNK_PX + tid * PX;
    const size_t base = (size_t)b * HW_ + hw0;
    const float  sigma = expf(log_sigma_p[0]);

    // ---- colour head for my 2 pixels (kept in registers) ----
    float col[NC][PX];
#pragma unroll
    for (int c = 0; c < NC; ++c) { col[c][0] = 0.f; col[c][1] = 0.f; }

    const float* fb = feat + (size_t)b * NF * HW_ + hw0;
    for (int f = 0; f < NF; ++f) {
        float2 v = *reinterpret_cast<const float2*>(fb + (size_t)f * HW_);
#pragma unroll
        for (int c = 0; c < NC; ++c) {
            float w = sW[c * NF + f];
            col[c][0] = fmaf(v.x, w, col[c][0]);
            col[c][1] = fmaf(v.y, w, col[c][1]);
        }
    }
    {
        float* cb = colour + (size_t)b * NC * HW_ + hw0;
#pragma unroll
        for (int c = 0; c < NC; ++c) {
            col[c][0] += sB[c]; col[c][1] += sB[c];
            float2 o = make_float2(col[c][0], col[c][1]);
            *reinterpret_cast<float2*>(cb + (size_t)c * HW_) = o;
        }
    }

    // ---- rand + log_s state; materialize log_s_k[0] = 0 ----
    float rp[PX];
    {
        float2 r2 = *reinterpret_cast<const float2*>(rand_pix + base);
        rp[0] = r2.x; rp[1] = r2.y;
    }
    float ls[PX] = {0.f, 0.f};
    *reinterpret_cast<float2*>(log_s_k + base) = make_float2(0.f, 0.f);

    // ---- initial partial argmax (scope==1 -> p = rand) into buffer 0 ----
    {
        float bv = rp[0]; int bi = hw0;
        argmax_cmp(bv, bi, rp[1], hw0 + 1);
        wave_argmax(bv, bi);
        if (lane == 0) { swv[wid] = bv; swi[wid] = bi; }
        __syncthreads();
        if (tid == 0) {
            float v = swv[0]; int ii = swi[0];
#pragma unroll
            for (int w = 1; w < NT / 64; ++w) argmax_cmp(v, ii, swv[w], swi[w]);
            pv[b * NCHUNK + chunk] = v;
            pi[b * NCHUNK + chunk] = ii;
        }
    }
    grid.sync();

    // ---- 8 scan steps ----
    for (int k = 0; k < NK; ++k) {
        const int cur = k & 1, nxt = cur ^ 1;
        const float* pvc = pv + cur * NB * NCHUNK;
        const int*   pic = pi + cur * NB * NCHUNK;

        // cross-block argmax reduce (wave 0 only), broadcast via LDS
        if (wid == 0) {
            float v0 = pvc[b * NCHUNK + lane];
            int   i0 = pic[b * NCHUNK + lane];
            float v1 = pvc[b * NCHUNK + 64 + lane];
            int   i1 = pic[b * NCHUNK + 64 + lane];
            argmax_cmp(v0, i0, v1, i1);
            wave_argmax(v0, i0);
            if (lane == 0) { sRes = v0; sResI = i0; }
        }
        __syncthreads();
        const int idx = sResI;

        if (tid < NC) {
            float sc = colour[((size_t)b * NC + tid) * HW_ + idx];
            sSeed[tid] = sc;
            if (chunk == 0) seeds[((size_t)k * NB + b) * NC + tid] = sc;
        }
        __syncthreads();

        // per-pixel update (everything in registers)
        float lm[PX], ln[PX];
#pragma unroll
        for (int p = 0; p < PX; ++p) {
            float d = 0.f;
#pragma unroll
            for (int c = 0; c < NC; ++c) {
                float diff = col[c][p] - sSeed[c];
                d = fmaf(diff, diff, d);
            }
            float a = expf(-d / sigma);
            a = fminf(fmaxf(a, 0.01f), 0.99f);
            lm[p] = ls[p] + logf(a);
            ln[p] = ls[p] + logf(1.0f - a);
        }

        *reinterpret_cast<float2*>(log_m_k + (size_t)k * NB * HW_ + base) =
            make_float2(lm[0], lm[1]);
        *reinterpret_cast<float2*>(log_s_k + (size_t)(k + 1) * NB * HW_ + base) =
            make_float2(ln[0], ln[1]);
        if (k == NK - 1) {
            // log_m_k[K] = last_log_s
            *reinterpret_cast<float2*>(log_m_k + (size_t)NK * NB * HW_ + base) =
                make_float2(ln[0], ln[1]);
        }
        ls[0] = ln[0]; ls[1] = ln[1];

        if (k < NK - 1) {
            // fused partial argmax for the NEXT step: p = rand * exp(log_s_new)
            float p0 = rp[0] * expf(ln[0]);
            float p1 = rp[1] * expf(ln[1]);
            float bv = p0; int bi = hw0;
            argmax_cmp(bv, bi, p1, hw0 + 1);
            wave_argmax(bv, bi);
            __syncthreads();   // protect swv/swi reuse (tid0 read above done pre-grid-sync edge)
            if (lane == 0) { swv[wid] = bv; swi[wid] = bi; }
            __syncthreads();
            if (tid == 0) {
                float v = swv[0]; int ii = swi[0];
#pragma unroll
                for (int w = 1; w < NT / 64; ++w) argmax_cmp(v, ii, swv[w], swi[w]);
                pv[nxt * NB * NCHUNK + b * NCHUNK + chunk] = v;
                pi[nxt * NB * NCHUNK + b * NCHUNK + chunk] = ii;
            }
            grid.sync();
        }
    }
}

// ---------------------------------------------------------------------------
extern "C" void kernel_launch(void* const* d_in, const int* in_sizes, int n_in,
                              void* d_out, int out_size, void* d_ws, size_t ws_size,
                              hipStream_t stream) {
    const float* feat      = (const float*)d_in[0];  // [8,64,256,256]
    const float* Wm        = (const float*)d_in[1];  // [8,64]
    const float* bias      = (const float*)d_in[2];  // [8]
    const float* log_sigma = (const float*)d_in[3];  // [1]
    const float* rand_pix  = (const float*)d_in[4];  // [8,1,256,256]
    // d_in[5] = steps_to_run (== NK, fixed)

    float* out     = (float*)d_out;
    float* log_m_k = out;              // (NK+1)*NB*HW_
    float* log_s_k = out + LMK_SZ;     // (NK+1)*NB*HW_
    float* colour  = out + 2 * LMK_SZ; // NB*NC*HW_
    float* seeds   = colour + COL_SZ;  // NK*NB*NC

    // workspace: double-buffered argmax partials
    float* pv = (float*)d_ws;                               // [2][NB][NCHUNK]
    int*   pi = (int*)((char*)d_ws + 2 * NB * NCHUNK * 4);  // [2][NB][NCHUNK]

    void* args[] = {
        (void*)&feat, (void*)&Wm, (void*)&bias, (void*)&log_sigma, (void*)&rand_pix,
        (void*)&log_m_k, (void*)&log_s_k, (void*)&colour, (void*)&seeds,
        (void*)&pv, (void*)&pi,
    };
    hipLaunchCooperativeKernel((const void*)fused_sbp_kernel,
                               dim3(NCHUNK, NB), dim3(NT), args, 0, stream);
}

// Round 5
// 267.026 us; speedup vs baseline: 4.1587x; 4.1587x over previous
//
#include <hip/hip_runtime.h>
#include <cstdint>
#include <cstddef>

// Problem constants (fixed by reference setup_inputs)
#define HW_      65536     // 256*256
#define NB       8         // batch
#define NC       8         // colour dim
#define NF       64        // feature dim
#define NK       8         // K_STEPS
#define NT       256       // threads per block

// colour kernel: 4 px/thread (float4), 64 chunks/batch -> 512 blocks
#define CPX4     (NT * 4)
#define NCH4     (HW_ / CPX4)
// init/step kernels: 2 px/thread (float2), 128 chunks/batch -> 1024 blocks
#define PX       2
#define CHUNK_PX (NT * PX)
#define NCHUNK   (HW_ / CHUNK_PX)

// log(0.01f), log(0.99f)
#define LN_LO  (-4.6051702f)
#define LN_HI  (-0.010050336f)

// d_out layout (floats):
//   log_m_k : (NK+1)*NB*HW_
//   log_s_k : (NK+1)*NB*HW_
//   colour  : NB*NC*HW_
//   seeds   : NK*NB*NC
#define LMK_SZ ((size_t)(NK + 1) * NB * HW_)
#define COL_SZ ((size_t)NB * NC * HW_)

__device__ __forceinline__ void argmax_cmp(float& bv, int& bi, float ov, int oi) {
    if (ov > bv || (ov == bv && oi < bi)) { bv = ov; bi = oi; }
}

__device__ __forceinline__ void wave_argmax(float& bv, int& bi) {
#pragma unroll
    for (int off = 32; off > 0; off >>= 1) {
        float ov = __shfl_down(bv, off);
        int   oi = __shfl_down(bi, off);
        argmax_cmp(bv, bi, ov, oi);
    }
}

// ---------------------------------------------------------------------------
// Kernel 1: colour = einsum('bfhw,cf->bchw', features, W) + b   (unchanged)
// ---------------------------------------------------------------------------
__global__ __launch_bounds__(NT)
void colour_kernel(const float* __restrict__ feat, const float* __restrict__ Wm,
                   const float* __restrict__ bias, float* __restrict__ colour) {
    __shared__ float sW[NC * NF];
    __shared__ float sB[NC];
    int tid = threadIdx.x;
    for (int i = tid; i < NC * NF; i += NT) sW[i] = Wm[i];
    if (tid < NC) sB[tid] = bias[tid];
    __syncthreads();

    int b   = blockIdx.y;
    int hw0 = blockIdx.x * CPX4 + tid * 4;
    const float* fb = feat + (size_t)b * NF * HW_ + hw0;

    float4 acc[NC];
#pragma unroll
    for (int c = 0; c < NC; ++c) acc[c] = make_float4(0.f, 0.f, 0.f, 0.f);

    for (int f = 0; f < NF; ++f) {
        float4 v = *reinterpret_cast<const float4*>(fb + (size_t)f * HW_);
#pragma unroll
        for (int c = 0; c < NC; ++c) {
            float w = sW[c * NF + f];
            acc[c].x = fmaf(v.x, w, acc[c].x);
            acc[c].y = fmaf(v.y, w, acc[c].y);
            acc[c].z = fmaf(v.z, w, acc[c].z);
            acc[c].w = fmaf(v.w, w, acc[c].w);
        }
    }

    float* cb = colour + (size_t)b * NC * HW_ + hw0;
#pragma unroll
    for (int c = 0; c < NC; ++c) {
        float4 o = acc[c];
        float bc = sB[c];
        o.x += bc; o.y += bc; o.z += bc; o.w += bc;
        *reinterpret_cast<float4*>(cb + (size_t)c * HW_) = o;
    }
}

// ---------------------------------------------------------------------------
// Kernel 2: per-chunk argmax partials for step 0 (scope == 1 -> p = rand)
// ---------------------------------------------------------------------------
__global__ __launch_bounds__(NT)
void init_argmax_kernel(const float* __restrict__ rand_pix,
                        float* __restrict__ pv, int* __restrict__ pi) {
    int b = blockIdx.y, chunk = blockIdx.x, tid = threadIdx.x;
    int lane = tid & 63, wid = tid >> 6;
    int hw0 = chunk * CHUNK_PX + tid * PX;

    float2 r = *reinterpret_cast<const float2*>(rand_pix + (size_t)b * HW_ + hw0);
    float bv = r.x; int bi = hw0;
    argmax_cmp(bv, bi, r.y, hw0 + 1);
    wave_argmax(bv, bi);

    __shared__ float swv[NT / 64];
    __shared__ int   swi[NT / 64];
    if (lane == 0) { swv[wid] = bv; swi[wid] = bi; }
    __syncthreads();
    if (tid == 0) {
        float v = swv[0]; int ii = swi[0];
#pragma unroll
        for (int w = 1; w < NT / 64; ++w) argmax_cmp(v, ii, swv[w], swi[w]);
        pv[b * NCHUNK + chunk] = v;
        pi[b * NCHUNK + chunk] = ii;
    }
}

// ---------------------------------------------------------------------------
// Kernel 3: one scan step (2 px/thread, 1024 blocks).
//  - issue all per-pixel loads up front (hide latency under the reduce)
//  - wave 0 reduces 128 partials -> idx; gather seed; chunk 0 writes seeds
//  - elementwise update; fused partial argmax for the next step
// ---------------------------------------------------------------------------
__global__ __launch_bounds__(NT)
void step_kernel(const float* __restrict__ colour, const float* __restrict__ rand_pix,
                 const float* __restrict__ log_sigma_p,
                 float* __restrict__ log_m_k, float* __restrict__ log_s_k,
                 float* __restrict__ seeds,
                 const float* __restrict__ pv_in, const int* __restrict__ pi_in,
                 float* __restrict__ pv_out, int* __restrict__ pi_out,
                 int k) {
    const int b = blockIdx.y, chunk = blockIdx.x, tid = threadIdx.x;
    const int lane = tid & 63, wid = tid >> 6;

    const int    hw0  = chunk * CHUNK_PX + tid * PX;
    const size_t base = (size_t)b * HW_ + hw0;

    __shared__ float sSeed[NC];
    __shared__ float swv[NT / 64];
    __shared__ int   swi[NT / 64];
    __shared__ int   sResI;

    // ---- issue independent per-pixel loads first ----
    float cv[NC][PX];
    const float* cb = colour + (size_t)b * NC * HW_ + hw0;
#pragma unroll
    for (int c = 0; c < NC; ++c) {
        float2 v = *reinterpret_cast<const float2*>(cb + (size_t)c * HW_);
        cv[c][0] = v.x; cv[c][1] = v.y;
    }
    float2 r2 = *reinterpret_cast<const float2*>(rand_pix + base);
    float ls0, ls1;
    if (k == 0) {
        ls0 = 0.f; ls1 = 0.f;
        *reinterpret_cast<float2*>(log_s_k + base) = make_float2(0.f, 0.f);
    } else {
        float2 l2 = *reinterpret_cast<const float2*>(log_s_k + (size_t)k * NB * HW_ + base);
        ls0 = l2.x; ls1 = l2.y;
    }
    const float inv_sigma = expf(-log_sigma_p[0]);   // 1/sigma

    // ---- cross-block argmax reduce (wave 0), hide loads above under it ----
    if (wid == 0) {
        float v0 = pv_in[b * NCHUNK + lane];
        int   i0 = pi_in[b * NCHUNK + lane];
        float v1 = pv_in[b * NCHUNK + 64 + lane];
        int   i1 = pi_in[b * NCHUNK + 64 + lane];
        argmax_cmp(v0, i0, v1, i1);
        wave_argmax(v0, i0);
        if (lane == 0) sResI = i0;
    }
    __syncthreads();
    const int idx = sResI;

    if (tid < NC) {
        float sc = colour[((size_t)b * NC + tid) * HW_ + idx];
        sSeed[tid] = sc;
        if (chunk == 0) seeds[((size_t)k * NB + b) * NC + tid] = sc;
    }
    __syncthreads();

    // ---- per-pixel update ----
    float lm[PX], ln_[PX];
#pragma unroll
    for (int p = 0; p < PX; ++p) {
        float d = 0.f;
#pragma unroll
        for (int c = 0; c < NC; ++c) {
            float diff = cv[c][p] - sSeed[c];
            d = fmaf(diff, diff, d);
        }
        float t = -d * inv_sigma;                       // log(alpha) pre-clamp
        float tc = fminf(fmaxf(t, LN_LO), LN_HI);       // log(clip(alpha))
        float a  = expf(tc);                            // clipped alpha
        float lsp = (p == 0) ? ls0 : ls1;
        lm[p]  = lsp + tc;
        ln_[p] = lsp + logf(1.0f - a);
    }

    *reinterpret_cast<float2*>(log_m_k + (size_t)k * NB * HW_ + base) =
        make_float2(lm[0], lm[1]);
    *reinterpret_cast<float2*>(log_s_k + (size_t)(k + 1) * NB * HW_ + base) =
        make_float2(ln_[0], ln_[1]);
    if (k == NK - 1) {
        // log_m_k[K] = last_log_s
        *reinterpret_cast<float2*>(log_m_k + (size_t)NK * NB * HW_ + base) =
            make_float2(ln_[0], ln_[1]);
    } else {
        // ---- fused partial argmax for next step: p = rand * exp(log_s_new) ----
        float p0 = r2.x * expf(ln_[0]);
        float p1 = r2.y * expf(ln_[1]);
        float bv = p0; int bi = hw0;
        argmax_cmp(bv, bi, p1, hw0 + 1);
        wave_argmax(bv, bi);
        if (lane == 0) { swv[wid] = bv; swi[wid] = bi; }
        __syncthreads();
        if (tid == 0) {
            float v = swv[0]; int ii = swi[0];
#pragma unroll
            for (int w = 1; w < NT / 64; ++w) argmax_cmp(v, ii, swv[w], swi[w]);
            pv_out[b * NCHUNK + chunk] = v;
            pi_out[b * NCHUNK + chunk] = ii;
        }
    }
}

// ---------------------------------------------------------------------------
extern "C" void kernel_launch(void* const* d_in, const int* in_sizes, int n_in,
                              void* d_out, int out_size, void* d_ws, size_t ws_size,
                              hipStream_t stream) {
    const float* feat      = (const float*)d_in[0];  // [8,64,256,256]
    const float* Wm        = (const float*)d_in[1];  // [8,64]
    const float* bias      = (const float*)d_in[2];  // [8]
    const float* log_sigma = (const float*)d_in[3];  // [1]
    const float* rand_pix  = (const float*)d_in[4];  // [8,1,256,256]
    // d_in[5] = steps_to_run (== NK, fixed)

    float* out     = (float*)d_out;
    float* log_m_k = out;              // (NK+1)*NB*HW_
    float* log_s_k = out + LMK_SZ;     // (NK+1)*NB*HW_
    float* colour  = out + 2 * LMK_SZ; // NB*NC*HW_
    float* seeds   = colour + COL_SZ;  // NK*NB*NC

    // workspace: double-buffered argmax partials
    float* pv = (float*)d_ws;                               // [2][NB][NCHUNK]
    int*   pi = (int*)((char*)d_ws + 2 * NB * NCHUNK * 4);  // [2][NB][NCHUNK]

    colour_kernel<<<dim3(NCH4, NB), NT, 0, stream>>>(feat, Wm, bias, colour);
    init_argmax_kernel<<<dim3(NCHUNK, NB), NT, 0, stream>>>(rand_pix, pv, pi);

    for (int k = 0; k < NK; ++k) {
        int cur = k & 1, nxt = cur ^ 1;
        step_kernel<<<dim3(NCHUNK, NB), NT, 0, stream>>>(
            colour, rand_pix, log_sigma,
            log_m_k, log_s_k, seeds,
            pv + cur * NB * NCHUNK, pi + cur * NB * NCHUNK,
            pv + nxt * NB * NCHUNK, pi + nxt * NB * NCHUNK,
            k);
    }
}